// Round 7
// baseline (187.737 us; speedup 1.0000x reference)
//
#include <hip/hip_runtime.h>
#include <hip/hip_bf16.h>

#define BB 4
#define CC 128
#define NN 4096
#define CK 32
#define L2E 1.442695040888963f

typedef __attribute__((ext_vector_type(8))) short short8v;
typedef __attribute__((ext_vector_type(4))) float float4v;

__device__ inline ushort f2bf(float f) {
    union { __hip_bfloat16 h; ushort u; } cv;
    cv.h = __float2bfloat16(f);
    return cv.u;
}
__device__ inline uint pk2(float lo, float hi) {
    return ((uint)f2bf(lo)) | ((uint)f2bf(hi) << 16);
}

// ---------------------------------------------------------------------------
// Kernel 1: projections -> bf16.  ft/gt [b][n][32] (MFMA-fragment-contiguous),
// v [b][c][n] with sign(gamma) folded in.
// ---------------------------------------------------------------------------
__global__ __launch_bounds__(256) void proj_kernel(
    const float* __restrict__ x,
    const float* __restrict__ Wf, const float* __restrict__ bf,
    const float* __restrict__ Wg, const float* __restrict__ bg,
    const float* __restrict__ Wh, const float* __restrict__ bh,
    const float* __restrict__ gamma,
    ushort* __restrict__ ft, ushort* __restrict__ gt, ushort* __restrict__ vh)
{
    __shared__ float xs[CC][64];
    const int t  = threadIdx.x;
    const int n0 = blockIdx.x * 64;
    const int b  = blockIdx.y;
    const float* xb = x + (size_t)b * CC * NN + n0;

    {
        const int j = t & 63;
        #pragma unroll
        for (int i = 0; i < 32; ++i) {
            const int c = (t >> 6) + 4 * i;
            xs[c][j] = xb[(size_t)c * NN + j];
        }
    }
    __syncthreads();

    const int jq = t & 15;
    const int og = t >> 4;

    float acc[12][4];
    #pragma unroll
    for (int i = 0; i < 12; ++i)
        #pragma unroll
        for (int jj = 0; jj < 4; ++jj) acc[i][jj] = 0.f;

    for (int c = 0; c < CC; ++c) {
        const float4 xv = *reinterpret_cast<const float4*>(&xs[c][jq * 4]);
        #pragma unroll
        for (int i = 0; i < 12; ++i) {
            const int o = og + 16 * i;
            float w;
            if (i < 2)       w = Wf[o * CC + c];
            else if (i < 4)  w = Wg[(o - 32) * CC + c];
            else             w = Wh[(o - 64) * CC + c];
            acc[i][0] += w * xv.x;
            acc[i][1] += w * xv.y;
            acc[i][2] += w * xv.z;
            acc[i][3] += w * xv.w;
        }
    }

    const float sgn = (gamma[0] < 0.f) ? -1.f : 1.f;
    const int n_base = n0 + jq * 4;
    #pragma unroll
    for (int i = 0; i < 2; ++i) {
        const int o = og + 16 * i;
        const float bias = bf[o];
        #pragma unroll
        for (int jj = 0; jj < 4; ++jj)
            ft[((size_t)b * NN + n_base + jj) * CK + o] = f2bf(acc[i][jj] + bias);
    }
    #pragma unroll
    for (int i = 2; i < 4; ++i) {
        const int o = og + 16 * (i - 2);
        const float bias = bg[o];
        #pragma unroll
        for (int jj = 0; jj < 4; ++jj)
            gt[((size_t)b * NN + n_base + jj) * CK + o] = f2bf(acc[i][jj] + bias);
    }
    #pragma unroll
    for (int i = 4; i < 12; ++i) {
        const int c = og + 16 * (i - 4);
        const float bias = bh[c];
        ushort4 pkv;
        pkv.x = f2bf(sgn * (acc[i][0] + bias));
        pkv.y = f2bf(sgn * (acc[i][1] + bias));
        pkv.z = f2bf(sgn * (acc[i][2] + bias));
        pkv.w = f2bf(sgn * (acc[i][3] + bias));
        *reinterpret_cast<ushort4*>(&vh[((size_t)b * CC + c) * NN + n_base]) = pkv;
    }
}

// ---------------------------------------------------------------------------
// Kernel 2: partial softmax denominators via MFMA, double-buffered b-frags.
// Grid (N/64, B, 4 m-chunks).
// ---------------------------------------------------------------------------
__global__ __launch_bounds__(256) void pass1_kernel(
    const ushort* __restrict__ ft, const ushort* __restrict__ gt,
    float* __restrict__ Dpart)
{
    const int t   = threadIdx.x;
    const int w   = t >> 6;
    const int l   = t & 63;
    const int g16 = l >> 4;
    const int l16 = l & 15;
    const int n0  = blockIdx.x * 64;
    const int b   = blockIdx.y;
    const int mz  = blockIdx.z;

    const ushort* ftb = ft + (size_t)b * NN * CK;
    const ushort* gtb = gt + (size_t)b * NN * CK;

    const short8v afrag = *reinterpret_cast<const short8v*>(
        &ftb[(size_t)(n0 + 16 * w + l16) * CK + 8 * g16]);

    const float4v zf = {0.f, 0.f, 0.f, 0.f};
    float d0 = 0.f, d1 = 0.f, d2 = 0.f, d3 = 0.f;
    const int m0 = mz * 1024;

    short8v bfA = *reinterpret_cast<const short8v*>(
        &gtb[(size_t)(m0 + l16) * CK + 8 * g16]);
    #pragma unroll 1
    for (int mt = 0; mt < 64; mt += 2) {
        const short8v bfB = *reinterpret_cast<const short8v*>(
            &gtb[(size_t)(m0 + (mt + 1) * 16 + l16) * CK + 8 * g16]);
        float4v s = __builtin_amdgcn_mfma_f32_16x16x32_bf16(afrag, bfA, zf, 0, 0, 0);
        d0 += __expf(s[0]); d1 += __expf(s[1]); d2 += __expf(s[2]); d3 += __expf(s[3]);
        bfA = *reinterpret_cast<const short8v*>(
            &gtb[(size_t)(m0 + (((mt + 2) & 63)) * 16 + l16) * CK + 8 * g16]);
        float4v s2 = __builtin_amdgcn_mfma_f32_16x16x32_bf16(afrag, bfB, zf, 0, 0, 0);
        d0 += __expf(s2[0]); d1 += __expf(s2[1]); d2 += __expf(s2[2]); d3 += __expf(s2[3]);
    }
    #pragma unroll
    for (int msk = 1; msk <= 8; msk <<= 1) {
        d0 += __shfl_xor(d0, msk);
        d1 += __shfl_xor(d1, msk);
        d2 += __shfl_xor(d2, msk);
        d3 += __shfl_xor(d3, msk);
    }
    if (l16 < 4) {
        const int n = n0 + 16 * w + 4 * g16 + l16;
        const float v = (l16 == 0) ? d0 : (l16 == 1) ? d1 : (l16 == 2) ? d2 : d3;
        Dpart[((size_t)b * NN + n) * 4 + mz] = v;
    }
}

// ---------------------------------------------------------------------------
// Kernel 3: Ld = log2(|gamma| / D)   (sign of gamma folded into V)
// ---------------------------------------------------------------------------
__global__ __launch_bounds__(256) void reduce_kernel(
    const float* __restrict__ Dpart, float* __restrict__ Ld,
    const float* __restrict__ gamma)
{
    const int i = blockIdx.x * 256 + threadIdx.x;
    const float4 d4 = *reinterpret_cast<const float4*>(&Dpart[(size_t)i * 4]);
    const float D = d4.x + d4.y + d4.z + d4.w;
    Ld[i] = log2f(fabsf(gamma[0])) - log2f(D);
}

// ---------------------------------------------------------------------------
// Kernel 4: PV with sigma-permuted K (S output frag IS the PV B-frag; no
// cross-lane relayout).  BM=32, 512 blocks (2/CU), 512 thr (8 waves),
// __launch_bounds__(512,4) -> 4 waves/SIMD for latency hiding.
// wave = (c-half ch, n-quarter nq).  Per 32-n step: 4 S-MFMA + 16 exp2 +
// 8 PV-MFMA + 12 plain loads (TLP hides L2 latency).
// Epilogue: two-round cross-nq reduction in 32 KB LDS.
// ---------------------------------------------------------------------------
__global__ __launch_bounds__(512, 4) void pass2_kernel(
    const ushort* __restrict__ ft, const ushort* __restrict__ gt,
    const ushort* __restrict__ vh, const float* __restrict__ Ld,
    const float* __restrict__ x, float* __restrict__ out)
{
    __shared__ float4v rl[4][8][64];   // 32 KB epilogue deposit

    const int t   = threadIdx.x;
    const int w   = t >> 6;
    const int l   = t & 63;
    const int g16 = l >> 4;
    const int l16 = l & 15;
    const int ch  = w & 1;     // c-half: c in [64*ch, 64*ch+64)
    const int nq  = w >> 1;    // n-quarter

    const int bid = blockIdx.x;
    const int xcd = bid & 7;
    const int b   = xcd >> 1;
    const int m0  = ((bid >> 3) + 64 * (xcd & 1)) * 32;

    const ushort* ftb = ft + (size_t)b * NN * CK;
    const ushort* gtb = gt + (size_t)b * NN * CK;
    const ushort* vhb = vh + (size_t)b * CC * NN;
    const float*  ldb = Ld + (size_t)b * NN;

    short8v gfrag[2];
    #pragma unroll
    for (int tm = 0; tm < 2; ++tm)
        gfrag[tm] = *reinterpret_cast<const short8v*>(
            &gtb[(size_t)(m0 + 16 * tm + l16) * CK + 8 * g16]);

    const float4v zf = {0.f, 0.f, 0.f, 0.f};
    float4v acc[4][2];   // [tc][tm]
    #pragma unroll
    for (int tc = 0; tc < 4; ++tc)
        #pragma unroll
        for (int tm = 0; tm < 2; ++tm) acc[tc][tm] = zf;

    const int nbase = nq * 1024;

    #pragma unroll 1
    for (int st = 0; st < 32; ++st) {
        const int n0 = nbase + st * 32;

        const short8v af0 = *reinterpret_cast<const short8v*>(
            &ftb[(size_t)(n0 + l16) * CK + 8 * g16]);
        const short8v af1 = *reinterpret_cast<const short8v*>(
            &ftb[(size_t)(n0 + 16 + l16) * CK + 8 * g16]);
        const float4 ld0 = *reinterpret_cast<const float4*>(&ldb[n0 + 4 * g16]);
        const float4 ld1 = *reinterpret_cast<const float4*>(&ldb[n0 + 16 + 4 * g16]);

        uint2 vf[8];
        #pragma unroll
        for (int tc = 0; tc < 4; ++tc) {
            const size_t row = (size_t)(64 * ch + 16 * tc + l16) * NN;
            vf[2 * tc]     = *reinterpret_cast<const uint2*>(&vhb[row + n0 + 4 * g16]);
            vf[2 * tc + 1] = *reinterpret_cast<const uint2*>(&vhb[row + n0 + 16 + 4 * g16]);
        }

        // S = F^T G; P = exp2(S*log2e + Ld) packed bf16 -> PV B-frag directly
        union { uint u[4]; short8v s; } pf[2];
        #pragma unroll
        for (int tm = 0; tm < 2; ++tm) {
            float4v s0 = __builtin_amdgcn_mfma_f32_16x16x32_bf16(af0, gfrag[tm], zf, 0, 0, 0);
            float4v s1 = __builtin_amdgcn_mfma_f32_16x16x32_bf16(af1, gfrag[tm], zf, 0, 0, 0);
            pf[tm].u[0] = pk2(__builtin_amdgcn_exp2f(fmaf(s0[0], L2E, ld0.x)),
                              __builtin_amdgcn_exp2f(fmaf(s0[1], L2E, ld0.y)));
            pf[tm].u[1] = pk2(__builtin_amdgcn_exp2f(fmaf(s0[2], L2E, ld0.z)),
                              __builtin_amdgcn_exp2f(fmaf(s0[3], L2E, ld0.w)));
            pf[tm].u[2] = pk2(__builtin_amdgcn_exp2f(fmaf(s1[0], L2E, ld1.x)),
                              __builtin_amdgcn_exp2f(fmaf(s1[1], L2E, ld1.y)));
            pf[tm].u[3] = pk2(__builtin_amdgcn_exp2f(fmaf(s1[2], L2E, ld1.z)),
                              __builtin_amdgcn_exp2f(fmaf(s1[3], L2E, ld1.w)));
        }

        // PV: acc[c,m] += V[c, sigma(k)] * P[sigma(k), m]
        #pragma unroll
        for (int tc = 0; tc < 4; ++tc) {
            union { uint u[4]; short8v s; } av;
            av.u[0] = vf[2 * tc].x;     av.u[1] = vf[2 * tc].y;
            av.u[2] = vf[2 * tc + 1].x; av.u[3] = vf[2 * tc + 1].y;
            #pragma unroll
            for (int tm = 0; tm < 2; ++tm)
                acc[tc][tm] = __builtin_amdgcn_mfma_f32_16x16x32_bf16(av.s, pf[tm].s, acc[tc][tm], 0, 0, 0);
        }
    }

    // ---- epilogue: two-round cross-nq reduction (32 KB LDS, 3 barriers) ----
    if (nq >= 2) {
        const int slot = (nq - 2) * 2 + ch;
        #pragma unroll
        for (int tc = 0; tc < 4; ++tc)
            #pragma unroll
            for (int tm = 0; tm < 2; ++tm)
                rl[slot][tc * 2 + tm][l] = acc[tc][tm];
    }
    __syncthreads();
    if (nq < 2) {
        const int slot = nq * 2 + ch;
        #pragma unroll
        for (int tc = 0; tc < 4; ++tc)
            #pragma unroll
            for (int tm = 0; tm < 2; ++tm)
                acc[tc][tm] += rl[slot][tc * 2 + tm][l];
    }
    __syncthreads();
    if (nq == 1) {
        #pragma unroll
        for (int tc = 0; tc < 4; ++tc)
            #pragma unroll
            for (int tm = 0; tm < 2; ++tm)
                rl[ch][tc * 2 + tm][l] = acc[tc][tm];
    }
    __syncthreads();
    if (nq == 0) {
        const float* xb = x   + (size_t)b * CC * NN;
        float*       ob = out + (size_t)b * CC * NN;
        #pragma unroll
        for (int tc = 0; tc < 4; ++tc) {
            #pragma unroll
            for (int tm = 0; tm < 2; ++tm) {
                float4v s = acc[tc][tm] + rl[ch][tc * 2 + tm][l];
                const int cb = 64 * ch + 16 * tc + 4 * g16;
                const int m  = m0 + 16 * tm + l16;
                #pragma unroll
                for (int r = 0; r < 4; ++r) {
                    const size_t idx = (size_t)(cb + r) * NN + m;
                    ob[idx] = s[r] + xb[idx];
                }
            }
        }
    }
}

// ---------------------------------------------------------------------------
extern "C" void kernel_launch(void* const* d_in, const int* in_sizes, int n_in,
                              void* d_out, int out_size, void* d_ws, size_t ws_size,
                              hipStream_t stream)
{
    const float* x     = (const float*)d_in[0];
    const float* Wf    = (const float*)d_in[1];
    const float* bf    = (const float*)d_in[2];
    const float* Wg    = (const float*)d_in[3];
    const float* bg    = (const float*)d_in[4];
    const float* Wh    = (const float*)d_in[5];
    const float* bh    = (const float*)d_in[6];
    const float* gamma = (const float*)d_in[7];

    ushort* ft = (ushort*)d_ws;                    // [B][N][CK] bf16
    ushort* gt = ft + (size_t)BB * NN * CK;        // [B][N][CK] bf16
    ushort* vh = gt + (size_t)BB * NN * CK;        // [B][C][N]  bf16 (sign-folded)
    float* Dpart = (float*)(vh + (size_t)BB * CC * NN);  // [B*N][4]
    float* Ld    = Dpart + (size_t)BB * NN * 4;          // [B*N] log2(|g|/D)

    float* out = (float*)d_out;

    proj_kernel<<<dim3(NN / 64, BB), 256, 0, stream>>>(x, Wf, bf, Wg, bg, Wh, bh, gamma, ft, gt, vh);
    pass1_kernel<<<dim3(NN / 64, BB, 4), 256, 0, stream>>>(ft, gt, Dpart);
    reduce_kernel<<<dim3(BB * NN / 256), 256, 0, stream>>>(Dpart, Ld, gamma);
    pass2_kernel<<<dim3(512), 512, 0, stream>>>(ft, gt, vh, Ld, x, out);
}

// Round 8
// 97.193 us; speedup vs baseline: 1.9316x; 1.9316x over previous
//
#include <hip/hip_runtime.h>
#include <hip/hip_bf16.h>

#define BB 4
#define CC 128
#define NN 4096
#define CK 32
#define L2E 1.442695040888963f

typedef __attribute__((ext_vector_type(8))) short short8v;
typedef __attribute__((ext_vector_type(4))) float float4v;

__device__ inline ushort f2bf(float f) {
    union { __hip_bfloat16 h; ushort u; } cv;
    cv.h = __float2bfloat16(f);
    return cv.u;
}
__device__ inline uint pk2(float lo, float hi) {
    return ((uint)f2bf(lo)) | ((uint)f2bf(hi) << 16);
}
__device__ __forceinline__ void gll16(const void* g, void* l) {
    __builtin_amdgcn_global_load_lds(
        (const __attribute__((address_space(1))) void*)g,
        (__attribute__((address_space(3))) void*)l, 16, 0, 0);
}
__device__ __forceinline__ void gll4(const void* g, void* l) {
    __builtin_amdgcn_global_load_lds(
        (const __attribute__((address_space(1))) void*)g,
        (__attribute__((address_space(3))) void*)l, 4, 0, 0);
}

// ---------------------------------------------------------------------------
// Kernel 1: projections -> bf16.  ft/gt [b][n][32]; v [b][c][n], sign(gamma)
// folded in.
// ---------------------------------------------------------------------------
__global__ __launch_bounds__(256) void proj_kernel(
    const float* __restrict__ x,
    const float* __restrict__ Wf, const float* __restrict__ bf,
    const float* __restrict__ Wg, const float* __restrict__ bg,
    const float* __restrict__ Wh, const float* __restrict__ bh,
    const float* __restrict__ gamma,
    ushort* __restrict__ ft, ushort* __restrict__ gt, ushort* __restrict__ vh)
{
    __shared__ float xs[CC][64];
    const int t  = threadIdx.x;
    const int n0 = blockIdx.x * 64;
    const int b  = blockIdx.y;
    const float* xb = x + (size_t)b * CC * NN + n0;

    {
        const int j = t & 63;
        #pragma unroll
        for (int i = 0; i < 32; ++i) {
            const int c = (t >> 6) + 4 * i;
            xs[c][j] = xb[(size_t)c * NN + j];
        }
    }
    __syncthreads();

    const int jq = t & 15;
    const int og = t >> 4;

    float acc[12][4];
    #pragma unroll
    for (int i = 0; i < 12; ++i)
        #pragma unroll
        for (int jj = 0; jj < 4; ++jj) acc[i][jj] = 0.f;

    for (int c = 0; c < CC; ++c) {
        const float4 xv = *reinterpret_cast<const float4*>(&xs[c][jq * 4]);
        #pragma unroll
        for (int i = 0; i < 12; ++i) {
            const int o = og + 16 * i;
            float w;
            if (i < 2)       w = Wf[o * CC + c];
            else if (i < 4)  w = Wg[(o - 32) * CC + c];
            else             w = Wh[(o - 64) * CC + c];
            acc[i][0] += w * xv.x;
            acc[i][1] += w * xv.y;
            acc[i][2] += w * xv.z;
            acc[i][3] += w * xv.w;
        }
    }

    const float sgn = (gamma[0] < 0.f) ? -1.f : 1.f;
    const int n_base = n0 + jq * 4;
    #pragma unroll
    for (int i = 0; i < 2; ++i) {
        const int o = og + 16 * i;
        const float bias = bf[o];
        #pragma unroll
        for (int jj = 0; jj < 4; ++jj)
            ft[((size_t)b * NN + n_base + jj) * CK + o] = f2bf(acc[i][jj] + bias);
    }
    #pragma unroll
    for (int i = 2; i < 4; ++i) {
        const int o = og + 16 * (i - 2);
        const float bias = bg[o];
        #pragma unroll
        for (int jj = 0; jj < 4; ++jj)
            gt[((size_t)b * NN + n_base + jj) * CK + o] = f2bf(acc[i][jj] + bias);
    }
    #pragma unroll
    for (int i = 4; i < 12; ++i) {
        const int c = og + 16 * (i - 4);
        const float bias = bh[c];
        ushort4 pkv;
        pkv.x = f2bf(sgn * (acc[i][0] + bias));
        pkv.y = f2bf(sgn * (acc[i][1] + bias));
        pkv.z = f2bf(sgn * (acc[i][2] + bias));
        pkv.w = f2bf(sgn * (acc[i][3] + bias));
        *reinterpret_cast<ushort4*>(&vh[((size_t)b * CC + c) * NN + n_base]) = pkv;
    }
}

// ---------------------------------------------------------------------------
// Kernel 2: partial softmax denominators via MFMA.
// ---------------------------------------------------------------------------
__global__ __launch_bounds__(256) void pass1_kernel(
    const ushort* __restrict__ ft, const ushort* __restrict__ gt,
    float* __restrict__ Dpart)
{
    const int t   = threadIdx.x;
    const int w   = t >> 6;
    const int l   = t & 63;
    const int g16 = l >> 4;
    const int l16 = l & 15;
    const int n0  = blockIdx.x * 64;
    const int b   = blockIdx.y;
    const int mz  = blockIdx.z;

    const ushort* ftb = ft + (size_t)b * NN * CK;
    const ushort* gtb = gt + (size_t)b * NN * CK;

    const short8v afrag = *reinterpret_cast<const short8v*>(
        &ftb[(size_t)(n0 + 16 * w + l16) * CK + 8 * g16]);

    const float4v zf = {0.f, 0.f, 0.f, 0.f};
    float d0 = 0.f, d1 = 0.f, d2 = 0.f, d3 = 0.f;
    const int m0 = mz * 1024;

    short8v bfA = *reinterpret_cast<const short8v*>(
        &gtb[(size_t)(m0 + l16) * CK + 8 * g16]);
    #pragma unroll 1
    for (int mt = 0; mt < 64; mt += 2) {
        const short8v bfB = *reinterpret_cast<const short8v*>(
            &gtb[(size_t)(m0 + (mt + 1) * 16 + l16) * CK + 8 * g16]);
        float4v s = __builtin_amdgcn_mfma_f32_16x16x32_bf16(afrag, bfA, zf, 0, 0, 0);
        d0 += __expf(s[0]); d1 += __expf(s[1]); d2 += __expf(s[2]); d3 += __expf(s[3]);
        bfA = *reinterpret_cast<const short8v*>(
            &gtb[(size_t)(m0 + (((mt + 2) & 63)) * 16 + l16) * CK + 8 * g16]);
        float4v s2 = __builtin_amdgcn_mfma_f32_16x16x32_bf16(afrag, bfB, zf, 0, 0, 0);
        d0 += __expf(s2[0]); d1 += __expf(s2[1]); d2 += __expf(s2[2]); d3 += __expf(s2[3]);
    }
    #pragma unroll
    for (int msk = 1; msk <= 8; msk <<= 1) {
        d0 += __shfl_xor(d0, msk);
        d1 += __shfl_xor(d1, msk);
        d2 += __shfl_xor(d2, msk);
        d3 += __shfl_xor(d3, msk);
    }
    if (l16 < 4) {
        const int n = n0 + 16 * w + 4 * g16 + l16;
        const float v = (l16 == 0) ? d0 : (l16 == 1) ? d1 : (l16 == 2) ? d2 : d3;
        Dpart[((size_t)b * NN + n) * 4 + mz] = v;
    }
}

// ---------------------------------------------------------------------------
// Kernel 3: Ld = log2(|gamma| / D)
// ---------------------------------------------------------------------------
__global__ __launch_bounds__(256) void reduce_kernel(
    const float* __restrict__ Dpart, float* __restrict__ Ld,
    const float* __restrict__ gamma)
{
    const int i = blockIdx.x * 256 + threadIdx.x;
    const float4 d4 = *reinterpret_cast<const float4*>(&Dpart[(size_t)i * 4]);
    const float D = d4.x + d4.y + d4.z + d4.w;
    Ld[i] = log2f(fabsf(gamma[0])) - log2f(D);
}

// ---------------------------------------------------------------------------
// Kernel 4: sigma-permuted PV with WAVE-PRIVATE double-buffered LDS staging
// via global_load_lds (V 4KB + F 2KB + Ld 256B per 32-n step; 7 gll instrs),
// counted s_waitcnt vmcnt(7), ZERO barriers in the main loop.  V stored with
// even-XOR chunk swizzle (chunk ^ (row&6)) -> <=2-way ds_read_b64 conflicts.
// 256 blocks (1/CU), 8 waves = (ch, nq).  Epilogue reuses staging LDS.
// ---------------------------------------------------------------------------
#define V_OFF 0
#define F_OFF 4096
#define L_OFF 6144
#define BUFB  6400
#define WSTR  12800

__global__ __launch_bounds__(512) void pass2_kernel(
    const ushort* __restrict__ ft, const ushort* __restrict__ gt,
    const ushort* __restrict__ vh, const float* __restrict__ Ld,
    const float* __restrict__ x, float* __restrict__ out)
{
    __shared__ __align__(16) char smem[8 * WSTR];   // 100 KB

    const int t   = threadIdx.x;
    const int w   = t >> 6;
    const int l   = t & 63;
    const int g16 = l >> 4;
    const int l16 = l & 15;
    const int ch  = w & 1;     // c-half
    const int nq  = w >> 1;    // n-quarter

    const int bid = blockIdx.x;
    const int xcd = bid & 7;
    const int b   = xcd >> 1;
    const int m0  = ((bid >> 3) + 32 * (xcd & 1)) * 64;

    const ushort* ftb = ft + (size_t)b * NN * CK;
    const ushort* gtb = gt + (size_t)b * NN * CK;
    const ushort* vhb = vh + (size_t)b * CC * NN;
    const float*  ldb = Ld + (size_t)b * NN;

    char* wsm = smem + w * WSTR;

    short8v gfrag[4];
    #pragma unroll
    for (int tm = 0; tm < 4; ++tm)
        gfrag[tm] = *reinterpret_cast<const short8v*>(
            &gtb[(size_t)(m0 + 16 * tm + l16) * CK + 8 * g16]);

    const float4v zf = {0.f, 0.f, 0.f, 0.f};
    float4v acc[4][4];   // [tc][tm]
    #pragma unroll
    for (int tc = 0; tc < 4; ++tc)
        #pragma unroll
        for (int tm = 0; tm < 4; ++tm) acc[tc][tm] = zf;

    const int nbase = nq * 1024;
    const int rr = l >> 2, cp = l & 3;

#define STAGE(n0_, bo_) do {                                                   \
    _Pragma("unroll")                                                          \
    for (int j = 0; j < 4; ++j) {                                              \
        const int row = j * 16 + rr;                                           \
        gll16(vhb + (size_t)(64 * ch + row) * NN + (n0_)                       \
                  + (((2 * cp) ^ (row & 6)) << 2),                             \
              wsm + (bo_) + V_OFF + j * 1024);                                 \
    }                                                                          \
    _Pragma("unroll")                                                          \
    for (int j = 0; j < 2; ++j) {                                              \
        const int row = j * 16 + rr;                                           \
        gll16(ftb + (size_t)((n0_) + row) * CK + cp * 8,                       \
              wsm + (bo_) + F_OFF + j * 1024);                                 \
    }                                                                          \
    gll4(ldb + (n0_) + (l & 31), wsm + (bo_) + L_OFF);                         \
} while (0)

    // prologue: stage step 0, drain everything (incl. gfrag loads)
    STAGE(nbase, 0);
    asm volatile("s_waitcnt vmcnt(0)" ::: "memory");

    int bo = 0;
    #pragma unroll 1
    for (int st = 0; st < 32; ++st) {
        const int n0 = nbase + st * 32;
        if (st < 31) {
            STAGE(n0 + 32, bo ^ BUFB);
            asm volatile("s_waitcnt vmcnt(7)" ::: "memory");
        } else {
            asm volatile("s_waitcnt vmcnt(0)" ::: "memory");
        }

        const char*  Vb = wsm + bo + V_OFF;
        const char*  Fb = wsm + bo + F_OFF;
        const float* Lb = (const float*)(wsm + bo + L_OFF);

        const short8v af0 = *reinterpret_cast<const short8v*>(Fb + l16 * 64 + g16 * 16);
        const short8v af1 = *reinterpret_cast<const short8v*>(Fb + (16 + l16) * 64 + g16 * 16);
        const float4  ld0 = *reinterpret_cast<const float4*>(Lb + 4 * g16);
        const float4  ld1 = *reinterpret_cast<const float4*>(Lb + 16 + 4 * g16);

        // S = F^T G; P = exp2(S*log2e + Ld) packed bf16 -> PV B-frag directly
        union { uint u[4]; short8v s; } pf[4];
        #pragma unroll
        for (int tm = 0; tm < 4; ++tm) {
            float4v s0 = __builtin_amdgcn_mfma_f32_16x16x32_bf16(af0, gfrag[tm], zf, 0, 0, 0);
            float4v s1 = __builtin_amdgcn_mfma_f32_16x16x32_bf16(af1, gfrag[tm], zf, 0, 0, 0);
            pf[tm].u[0] = pk2(__builtin_amdgcn_exp2f(fmaf(s0[0], L2E, ld0.x)),
                              __builtin_amdgcn_exp2f(fmaf(s0[1], L2E, ld0.y)));
            pf[tm].u[1] = pk2(__builtin_amdgcn_exp2f(fmaf(s0[2], L2E, ld0.z)),
                              __builtin_amdgcn_exp2f(fmaf(s0[3], L2E, ld0.w)));
            pf[tm].u[2] = pk2(__builtin_amdgcn_exp2f(fmaf(s1[0], L2E, ld1.x)),
                              __builtin_amdgcn_exp2f(fmaf(s1[1], L2E, ld1.y)));
            pf[tm].u[3] = pk2(__builtin_amdgcn_exp2f(fmaf(s1[2], L2E, ld1.z)),
                              __builtin_amdgcn_exp2f(fmaf(s1[3], L2E, ld1.w)));
        }

        // PV: acc[c,m] += V[c, sigma(k)] * P[sigma(k), m]
        #pragma unroll
        for (int tc = 0; tc < 4; ++tc) {
            const int cl = 16 * tc + l16;
            const uint2 va = *reinterpret_cast<const uint2*>(
                Vb + cl * 64 + 8 * (g16 ^ (cl & 6)));
            const uint2 vb2 = *reinterpret_cast<const uint2*>(
                Vb + cl * 64 + 8 * ((4 + g16) ^ (cl & 6)));
            union { uint u[4]; short8v s; } av;
            av.u[0] = va.x;  av.u[1] = va.y;
            av.u[2] = vb2.x; av.u[3] = vb2.y;
            #pragma unroll
            for (int tm = 0; tm < 4; ++tm)
                acc[tc][tm] = __builtin_amdgcn_mfma_f32_16x16x32_bf16(av.s, pf[tm].s, acc[tc][tm], 0, 0, 0);
        }
        bo ^= BUFB;
    }
#undef STAGE

    // ---- epilogue: cross-nq reduction (staging LDS reused) ----
    __syncthreads();   // everyone done with private staging regions
    float4v* rl = (float4v*)smem;   // [6][16][64]
    if (nq != 0) {
        const int slot = (nq - 1) * 2 + ch;
        #pragma unroll
        for (int tc = 0; tc < 4; ++tc)
            #pragma unroll
            for (int tm = 0; tm < 4; ++tm)
                rl[(slot * 16 + tc * 4 + tm) * 64 + l] = acc[tc][tm];
    }
    __syncthreads();
    if (nq == 0) {
        const float* xb = x   + (size_t)b * CC * NN;
        float*       ob = out + (size_t)b * CC * NN;
        #pragma unroll
        for (int tc = 0; tc < 4; ++tc) {
            #pragma unroll
            for (int tm = 0; tm < 4; ++tm) {
                const int fi = tc * 4 + tm;
                float4v s = acc[tc][tm]
                          + rl[((ch) * 16 + fi) * 64 + l]
                          + rl[((2 + ch) * 16 + fi) * 64 + l]
                          + rl[((4 + ch) * 16 + fi) * 64 + l];
                const int cb = 64 * ch + 16 * tc + 4 * g16;
                const int m  = m0 + 16 * tm + l16;
                #pragma unroll
                for (int r = 0; r < 4; ++r) {
                    const size_t idx = (size_t)(cb + r) * NN + m;
                    ob[idx] = s[r] + xb[idx];
                }
            }
        }
    }
}

// ---------------------------------------------------------------------------
extern "C" void kernel_launch(void* const* d_in, const int* in_sizes, int n_in,
                              void* d_out, int out_size, void* d_ws, size_t ws_size,
                              hipStream_t stream)
{
    const float* x     = (const float*)d_in[0];
    const float* Wf    = (const float*)d_in[1];
    const float* bf    = (const float*)d_in[2];
    const float* Wg    = (const float*)d_in[3];
    const float* bg    = (const float*)d_in[4];
    const float* Wh    = (const float*)d_in[5];
    const float* bh    = (const float*)d_in[6];
    const float* gamma = (const float*)d_in[7];

    ushort* ft = (ushort*)d_ws;                    // [B][N][CK] bf16
    ushort* gt = ft + (size_t)BB * NN * CK;        // [B][N][CK] bf16
    ushort* vh = gt + (size_t)BB * NN * CK;        // [B][C][N]  bf16 (sign-folded)
    float* Dpart = (float*)(vh + (size_t)BB * CC * NN);  // [B*N][4]
    float* Ld    = Dpart + (size_t)BB * NN * 4;          // [B*N] log2(|g|/D)

    float* out = (float*)d_out;

    proj_kernel<<<dim3(NN / 64, BB), 256, 0, stream>>>(x, Wf, bf, Wg, bg, Wh, bh, gamma, ft, gt, vh);
    pass1_kernel<<<dim3(NN / 64, BB, 4), 256, 0, stream>>>(ft, gt, Dpart);
    reduce_kernel<<<dim3(BB * NN / 256), 256, 0, stream>>>(Dpart, Ld, gamma);
    pass2_kernel<<<dim3(256), 512, 0, stream>>>(ft, gt, vh, Ld, x, out);
}